// Round 4
// baseline (39.123 us; speedup 1.0000x reference)
//
#include <hip/hip_runtime.h>

// StructOnlyClassifier R4: single fused kernel, one wave (64 lanes) per graph.
//  1. wave-parallel 64-ary lower_bound over sorted `batch` for S[g] and S[g+1]
//     (4 ballot rounds each for n=16M; top-level probe lines shared -> L2-hot)
//  2. coalesced int4 scan of the graph's contiguous node_type segment
//  3. in-wave 4->32->16->1 MLP (layer1 on 32 lanes, layer2 on 16, shfl reduce)
// No workspace, no atomics, one launch.

__device__ __forceinline__ int wave_lower_bound(
    const int* __restrict__ batch, int n, int g, int lane)
{
    // lb = first i in [0,n] with batch[i] >= g.  Invariant: lb in [lo, lo+sz].
    int lo = 0, sz = n;
    while (sz > 64) {
        const int step = sz >> 6;                 // >= 1
        const int idx  = lo + (lane + 1) * step;  // probes in (lo, lo+64*step]
        const bool pred = (idx < n) && (batch[idx] < g);
        const unsigned long long m = __ballot(pred);
        const int c = __popcll(m);                // # probes strictly below lb
        lo += c * step;
        sz = (c < 64) ? step : (sz - (c << 6) /* == 64*step */);
    }
    // final: sz <= 64, lb in [lo, lo+sz]
    const int idx = lo + lane;
    const bool pred = (lane < sz) && (idx < n) && (batch[idx] < g);
    return lo + __popcll(__ballot(pred));
}

__global__ __launch_bounds__(256) void fused_kernel(
    const int* __restrict__ batch, const int* __restrict__ ntype,
    const float* __restrict__ W1, const float* __restrict__ b1,
    const float* __restrict__ W2, const float* __restrict__ b2,
    const float* __restrict__ W3, const float* __restrict__ b3,
    float* __restrict__ out, int n, int B)
{
    const int t    = blockIdx.x * blockDim.x + threadIdx.x;
    const int g    = t >> 6;            // one wave per graph
    const int lane = t & 63;
    if (g >= B) return;

    const int s = wave_lower_bound(batch, n, g, lane);
    const int e = wave_lower_bound(batch, n, g + 1, lane);
    const int len = e - s;

    int c0 = 0, c1 = 0;

    int sa = (s + 3) & ~3; if (sa > e) sa = e;   // align-up head bound
    int ea = e & ~3;       if (ea < sa) ea = sa; // align-down tail bound

    // head scalars [s, sa)
    {
        const int i = s + lane;
        if (i < sa) { const int v = ntype[i]; c0 += (v == 0); c1 += (v == 1); }
    }
    // main int4 quads [sa, ea), lane-contiguous per iteration
    {
        const int4* nt4 = (const int4*)ntype;
        for (int q = (sa >> 2) + lane; q < (ea >> 2); q += 64) {
            const int4 v = nt4[q];
            c0 += (v.x == 0) + (v.y == 0) + (v.z == 0) + (v.w == 0);
            c1 += (v.x == 1) + (v.y == 1) + (v.z == 1) + (v.w == 1);
        }
    }
    // tail scalars [ea, e)
    {
        const int i = ea + lane;
        if (i < e) { const int v = ntype[i]; c0 += (v == 0); c1 += (v == 1); }
    }

    // wave-reduce both counts packed in one u64
    unsigned long long p = (unsigned)c0 | ((unsigned long long)(unsigned)c1 << 32);
    #pragma unroll
    for (int off = 32; off; off >>= 1) p += __shfl_xor(p, off);
    const int c0t = (int)(p & 0xFFFFFFFFull);
    const int c1t = (int)(p >> 32);

    const float f0 = (float)c0t - 54.5f;
    const float f1 = (float)c1t;
    const float f2 = (float)(len - c0t - c1t);
    const float f3 = (float)len - 56.5f;

    // layer 1: unit j on lane (lane&31); lanes 32-63 duplicate harmlessly
    const int j = lane & 31;
    float h1 = b1[j];
    h1 = fmaf(f0, W1[      j], h1);
    h1 = fmaf(f1, W1[ 32 + j], h1);
    h1 = fmaf(f2, W1[ 64 + j], h1);
    h1 = fmaf(f3, W1[ 96 + j], h1);
    h1 = fmaxf(0.0f, h1);

    // layer 2: unit m on lane (lane&15), broadcast h1 from lanes 0..31
    const int m = lane & 15;
    float s2 = b2[m];
    #pragma unroll
    for (int jj = 0; jj < 32; ++jj) {
        const float hj = __shfl(h1, jj);
        s2 = fmaf(hj, W2[jj * 16 + m], s2);
    }
    const float h2 = fmaxf(0.0f, s2);

    // layer 3: dot over 16 units via xor-reduce within 16-lane group
    float p3 = h2 * W3[m];
    p3 += __shfl_xor(p3, 8);
    p3 += __shfl_xor(p3, 4);
    p3 += __shfl_xor(p3, 2);
    p3 += __shfl_xor(p3, 1);

    if (lane == 0) out[g] = p3 + b3[0];
}

extern "C" void kernel_launch(void* const* d_in, const int* in_sizes, int n_in,
                              void* d_out, int out_size, void* d_ws, size_t ws_size,
                              hipStream_t stream) {
    // inputs: 0:x(N) 1:batch(N) 2:node_type(N) 3:num_graphs 4:W1 5:b1 6:W2 7:b2 8:W3 9:b3
    const int*   batch = (const int*)d_in[1];
    const int*   ntype = (const int*)d_in[2];
    const float* W1    = (const float*)d_in[4];
    const float* b1    = (const float*)d_in[5];
    const float* W2    = (const float*)d_in[6];
    const float* b2    = (const float*)d_in[7];
    const float* W3    = (const float*)d_in[8];
    const float* b3    = (const float*)d_in[9];
    float*       out   = (float*)d_out;

    const int n = in_sizes[1];          // 16,777,216 nodes
    const int B = out_size;             // 16,384 graphs

    const long long total = (long long)B * 64;   // one wave per graph
    const int blocks = (int)((total + 255) / 256);
    fused_kernel<<<blocks, 256, 0, stream>>>(
        batch, ntype, W1, b1, W2, b2, W3, b3, out, n, B);
}

// Round 5
// 29.144 us; speedup vs baseline: 1.3424x; 1.3424x over previous
//
#include <hip/hip_runtime.h>

// StructOnlyClassifier R5: two kernels.
//  A) bounds: S[g] = lower_bound(batch, g) via windowed binary search around
//     the statistical prediction g*(n/B) (sizes ~ Poisson(1024), sigma<=2042;
//     +-16384 = 8 sigma) with a deterministic bracket-verify + widen fallback.
//  B) seg_mlp: one wave per graph reads its contiguous node_type segment
//     (int4-coalesced), counts types, then a 4->32->16->1 MLP using LDS-staged
//     weights (W2 transposed, padded [16][36] -> 2-way-conflict float4 reads)
//     instead of R3's 32-deep shfl+fma chain.

__global__ __launch_bounds__(256) void bounds_kernel(
    const int* __restrict__ batch, int* __restrict__ S, int n, int B)
{
    const int g = blockIdx.x * blockDim.x + threadIdx.x;
    if (g > B) return;
    const long long c = (long long)g * (n / B);   // predicted S[g]
    int lo, hi;
    int W = 16384;                                 // 8 sigma half-window
    for (;;) {                                     // deterministic bracket
        long long l = c - W, h = c + W;
        lo = (l < 0) ? 0 : (int)l;
        hi = (h > n) ? n : (int)h;
        const bool okL = (lo == 0) || (batch[lo - 1] < g);
        const bool okR = (hi == n) || (batch[hi] >= g);
        if (okL && okR) break;
        W <<= 2;                                   // widens to [0,n] worst case
    }
    while (lo < hi) {
        const int mid = (lo + hi) >> 1;
        if (batch[mid] < g) lo = mid + 1;
        else                hi = mid;
    }
    S[g] = lo;
}

__global__ __launch_bounds__(256) void seg_mlp_kernel(
    const int* __restrict__ ntype, const int* __restrict__ S,
    const float* __restrict__ W1, const float* __restrict__ b1,
    const float* __restrict__ W2, const float* __restrict__ b2,
    const float* __restrict__ W3, const float* __restrict__ b3,
    float* __restrict__ out, int B)
{
    __shared__ __attribute__((aligned(16))) float sW1[128];
    __shared__ __attribute__((aligned(16))) float sW2T[16 * 36]; // [m][j], pad 36
    __shared__ __attribute__((aligned(16))) float sh1[4][32];    // per-wave h1
    __shared__ float sb1[32], sb2[16], sW3[16], sb3v[1];

    const int tid = threadIdx.x;
    if (tid < 128) sW1[tid] = W1[tid];
    for (int i = tid; i < 512; i += 256) {         // transpose W2 (32,16)
        const int j = i >> 4, m = i & 15;
        sW2T[m * 36 + j] = W2[i];
    }
    if      (tid < 32)  sb1[tid]       = b1[tid];
    else if (tid < 48)  sb2[tid - 32]  = b2[tid - 32];
    else if (tid < 64)  sW3[tid - 48]  = W3[tid - 48];
    else if (tid == 64) sb3v[0]        = b3[0];
    __syncthreads();

    const int w    = tid >> 6;
    const int lane = tid & 63;
    const int g    = blockIdx.x * 4 + w;
    const bool valid = (g < B);

    const int s = valid ? S[g]     : 0;
    const int e = valid ? S[g + 1] : 0;
    const int len = e - s;

    int c0 = 0, c1 = 0;
    int sa = (s + 3) & ~3; if (sa > e) sa = e;
    int ea = e & ~3;       if (ea < sa) ea = sa;

    {   // head scalars [s, sa)
        const int i = s + lane;
        if (i < sa) { const int v = ntype[i]; c0 += (v == 0); c1 += (v == 1); }
    }
    {   // main int4 quads [sa, ea)
        const int4* nt4 = (const int4*)ntype;
        for (int q = (sa >> 2) + lane; q < (ea >> 2); q += 64) {
            const int4 v = nt4[q];
            c0 += (v.x == 0) + (v.y == 0) + (v.z == 0) + (v.w == 0);
            c1 += (v.x == 1) + (v.y == 1) + (v.z == 1) + (v.w == 1);
        }
    }
    {   // tail scalars [ea, e)
        const int i = ea + lane;
        if (i < e) { const int v = ntype[i]; c0 += (v == 0); c1 += (v == 1); }
    }

    unsigned long long p = (unsigned)c0 | ((unsigned long long)(unsigned)c1 << 32);
    #pragma unroll
    for (int off = 32; off; off >>= 1) p += __shfl_xor(p, off);
    const int c0t = (int)(p & 0xFFFFFFFFull);
    const int c1t = (int)(p >> 32);

    const float f0 = (float)c0t - 54.5f;
    const float f1 = (float)c1t;
    const float f2 = (float)(len - c0t - c1t);
    const float f3 = (float)len - 56.5f;

    // layer 1: unit j on lane&31
    const int j = lane & 31;
    float h1 = sb1[j];
    h1 = fmaf(f0, sW1[      j], h1);
    h1 = fmaf(f1, sW1[ 32 + j], h1);
    h1 = fmaf(f2, sW1[ 64 + j], h1);
    h1 = fmaf(f3, sW1[ 96 + j], h1);
    h1 = fmaxf(0.0f, h1);
    if (lane < 32) sh1[w][j] = h1;
    __syncthreads();

    // layer 2: unit m on lane&15, float4 LDS reads (h broadcast, W2T 2-way)
    const int m = lane & 15;
    float s2 = sb2[m];
    const float4* h4  = (const float4*)&sh1[w][0];
    const float4* wt4 = (const float4*)&sW2T[m * 36];
    #pragma unroll
    for (int k = 0; k < 8; ++k) {
        const float4 a = h4[k];
        const float4 b = wt4[k];
        s2 = fmaf(a.x, b.x, s2);
        s2 = fmaf(a.y, b.y, s2);
        s2 = fmaf(a.z, b.z, s2);
        s2 = fmaf(a.w, b.w, s2);
    }
    const float h2 = fmaxf(0.0f, s2);

    // layer 3: reduce 16 units within the 16-lane group
    float p3 = h2 * sW3[m];
    p3 += __shfl_xor(p3, 1);
    p3 += __shfl_xor(p3, 2);
    p3 += __shfl_xor(p3, 4);
    p3 += __shfl_xor(p3, 8);

    if (valid && lane == 0) out[g] = p3 + sb3v[0];
}

extern "C" void kernel_launch(void* const* d_in, const int* in_sizes, int n_in,
                              void* d_out, int out_size, void* d_ws, size_t ws_size,
                              hipStream_t stream) {
    // inputs: 0:x(N) 1:batch(N) 2:node_type(N) 3:num_graphs 4:W1 5:b1 6:W2 7:b2 8:W3 9:b3
    const int*   batch = (const int*)d_in[1];
    const int*   ntype = (const int*)d_in[2];
    const float* W1    = (const float*)d_in[4];
    const float* b1    = (const float*)d_in[5];
    const float* W2    = (const float*)d_in[6];
    const float* b2    = (const float*)d_in[7];
    const float* W3    = (const float*)d_in[8];
    const float* b3    = (const float*)d_in[9];
    float*       out   = (float*)d_out;

    const int n = in_sizes[1];          // 16,777,216 nodes
    const int B = out_size;             // 16,384 graphs

    int* S = (int*)d_ws;                // B+1 ints

    bounds_kernel<<<(B + 1 + 255) / 256, 256, 0, stream>>>(batch, S, n, B);

    seg_mlp_kernel<<<(B + 3) / 4, 256, 0, stream>>>(
        ntype, S, W1, b1, W2, b2, W3, b3, out, B);
}